// Round 10
// baseline (140.782 us; speedup 1.0000x reference)
//
#include <hip/hip_runtime.h>
#include <math.h>

#define NROWS 16384
#define DDIM  256

typedef __attribute__((ext_vector_type(8))) short bf16x8;
typedef __attribute__((ext_vector_type(4))) float f32x4;
typedef __attribute__((ext_vector_type(4))) unsigned short us4;

__device__ __forceinline__ unsigned short bf16_rne(float f) {
  unsigned x = __float_as_uint(f);
  unsigned r = x + 0x7fffu + ((x >> 16) & 1u);
  return (unsigned short)(r >> 16);
}

typedef __attribute__((address_space(3))) unsigned int lds_uint;
typedef __attribute__((address_space(1))) const unsigned int glb_uint;
__device__ __forceinline__ void gload16(const void* g, void* l) {
  __builtin_amdgcn_global_load_lds((glb_uint*)g, (lds_uint*)l, 16, 0, 0);
}

// ------------- fused prep: embeds->bf16 hi  AND  padded -2W + ||w||^2 -------------
__global__ __launch_bounds__(256) void prep_all(const float* __restrict__ e,
                                                const float* __restrict__ cb0,
                                                const float* __restrict__ cb1,
                                                const float* __restrict__ cb2,
                                                unsigned short* __restrict__ ehi,
                                                unsigned short* __restrict__ W0,
                                                unsigned short* __restrict__ W12,
                                                float* __restrict__ wsq0,
                                                float* __restrict__ wsq12) {
  if (blockIdx.x < 2048) {
    int gid = blockIdx.x * 256 + threadIdx.x;
    const float4* p = reinterpret_cast<const float4*>(e) + (size_t)gid * 2;
    float4 a = p[0], b = p[1];
    float f[8] = {a.x, a.y, a.z, a.w, b.x, b.y, b.z, b.w};
    unsigned short hi[8];
    #pragma unroll
    for (int i = 0; i < 8; ++i) hi[i] = bf16_rne(f[i]);
    us4 h0 = {hi[0], hi[1], hi[2], hi[3]}, h1 = {hi[4], hi[5], hi[6], hi[7]};
    *reinterpret_cast<us4*>(&ehi[(size_t)gid * 8]) = h0;
    *reinterpret_cast<us4*>(&ehi[(size_t)gid * 8 + 4]) = h1;
    return;
  }
  int wv = threadIdx.x >> 6, ln = threadIdx.x & 63;
  int p = (blockIdx.x - 2048) * 4 + wv;          // 0..6655
  const float* src = nullptr; int local = 0;
  unsigned short* dst; float* wdst; int dcol;
  if (p < 6144) {
    dst = W0; wdst = wsq0; dcol = p;
    if (p < 5832) { src = cb0; local = p; }
  } else {
    int q = p - 6144;                            // 0..511
    dst = W12; wdst = wsq12; dcol = q;
    if (q < 324) { src = cb1; local = q; }
    else if (q >= 384 && q < 402) { src = cb2; local = q - 384; }
  }
  float4 f = make_float4(0.f, 0.f, 0.f, 0.f);
  if (src) f = *reinterpret_cast<const float4*>(src + (size_t)local * DDIM + ln * 4);
  // store -2w: MFMA then accumulates -2*e.w onto the ||w||^2 seed directly
  us4 h = {bf16_rne(-2.0f * f.x), bf16_rne(-2.0f * f.y),
           bf16_rne(-2.0f * f.z), bf16_rne(-2.0f * f.w)};
  *reinterpret_cast<us4*>(&dst[(size_t)dcol * DDIM + ln * 4]) = h;
  float s = f.x * f.x + f.y * f.y + f.z * f.z + f.w * f.w;
  #pragma unroll
  for (int m = 32; m > 0; m >>= 1) s += __shfl_xor(s, m);
  if (ln == 0) wdst[dcol] = src ? s : 1e38f;
}

// ------------- MFMA GEMM + in-lane packed-key top-2 scan -------------
// grid (128 rowblocks, 10 colgroups); 256 thr = 4 m-waves; wave = 32 rows x
// 64 cols; A full-K in VGPRs; B in 2x16KB LDS buffers: stage 4 / consume 4
// BK=32 chunks (32 MFMA) per barrier; acc seeded with ||w||^2.
__global__ __launch_bounds__(256, 4) void gemm_scan(
    const unsigned short* __restrict__ Ehi,
    const unsigned short* __restrict__ W0,
    const unsigned short* __restrict__ W12,
    const float* __restrict__ wsq0,
    const float* __restrict__ wsq12,
    float* __restrict__ ckeys) {
  __shared__ float smem[8192];                   // 32 KB: 2x16KB ring; merge unions
  unsigned short* Bs = reinterpret_cast<unsigned short*>(smem);

  const int tid = threadIdx.x;
  const int wm = tid >> 6, ln = tid & 63;
  const int t = ln & 15, lg = ln >> 4;
  const int rb = blockIdx.x, grp = blockIdx.y;

  const unsigned short* Wb; const float* wsqb; int nnt;
  if (grp < 8)       { Wb = W0 + (size_t)grp * 768 * 256; wsqb = wsq0 + grp * 768; nnt = 12; }
  else if (grp == 8) { Wb = W12;             wsqb = wsq12;       nnt = 6; }
  else               { Wb = W12 + 384 * 256; wsqb = wsq12 + 384; nnt = 1; }

  // A fragments: rows rb*128 + wm*32 + i*16 + t, k = ks*32 + lg*8 (full K in VGPRs)
  bf16x8 af[2][8];
  {
    const unsigned short* abase = Ehi + (size_t)(rb * 128 + wm * 32 + t) * 256 + lg * 8;
    #pragma unroll
    for (int i = 0; i < 2; ++i)
      #pragma unroll
      for (int ks = 0; ks < 8; ++ks)
        af[i][ks] = *reinterpret_cast<const bf16x8*>(abase + i * 16 * 256 + ks * 32);
  }

  // staging source (both-sides chunk swizzle; LDS dest stays linear)
  const int scol = tid >> 2;
  const int scs  = ((tid & 3) ^ ((scol >> 1) & 3)) * 8;

#define STAGE4(buf, cc0) do {                                                  \
    _Pragma("unroll")                                                          \
    for (int c = 0; c < 4; ++c) {                                              \
      const int cc = (cc0) + c;                                                \
      const unsigned short* wsrc = Wb + (cc >> 3) * (64 * 256) + (cc & 7) * 32;\
      gload16(wsrc + (size_t)scol * 256 + scs,                                 \
              Bs + ((buf) * 4 + c) * 2048 + tid * 8);                          \
    } } while (0)

  f32x4 acc[2][4];
  float s1[2][4], s2[2][4];
  #pragma unroll
  for (int i = 0; i < 2; ++i)
    #pragma unroll
    for (int r = 0; r < 4; ++r) { s1[i][r] = INFINITY; s2[i][r] = INFINITY; }

  const int nper = nnt * 2;                      // 4-chunk periods
  STAGE4(0, 0);
  __syncthreads();
  for (int ntl = 0; ntl < nnt; ++ntl) {
    float wq[4];
    #pragma unroll
    for (int j = 0; j < 4; ++j) wq[j] = wsqb[ntl * 64 + j * 16 + t];
    #pragma unroll
    for (int i = 0; i < 2; ++i)
      #pragma unroll
      for (int j = 0; j < 4; ++j)
        acc[i][j] = (f32x4){wq[j], wq[j], wq[j], wq[j]};   // seed with ||w||^2

    #pragma unroll
    for (int dd = 0; dd < 2; ++dd) {
      const int period = ntl * 2 + dd;
      if (period + 1 < nper) STAGE4((period + 1) & 1, (period + 1) * 4);
      const int bb = period & 1;
      #pragma unroll
      for (int c = 0; c < 4; ++c) {
        const int ks = dd * 4 + c;
        bf16x8 bfr[4];
        #pragma unroll
        for (int j = 0; j < 4; ++j) {
          int col = j * 16 + t;
          bfr[j] = *reinterpret_cast<const bf16x8*>(
              Bs + (bb * 4 + c) * 2048 + col * 32 + ((lg ^ ((col >> 1) & 3)) << 3));
        }
        #pragma unroll
        for (int i = 0; i < 2; ++i)
          #pragma unroll
          for (int j = 0; j < 4; ++j)
            acc[i][j] = __builtin_amdgcn_mfma_f32_16x16x32_bf16(af[i][ks], bfr[j], acc[i][j], 0, 0, 0);
      }
      __syncthreads();                           // staged quad landed; readers done
    }
    // scan: acc IS the distance; key = (acc & ~0xFFF) | local_col_idx
    {
      const unsigned lbase = (unsigned)(ntl * 64 + t);
      #pragma unroll
      for (int i = 0; i < 2; ++i)
        #pragma unroll
        for (int j = 0; j < 4; ++j) {
          const unsigned lidx = lbase + j * 16;
          #pragma unroll
          for (int r = 0; r < 4; ++r) {
            float key = __uint_as_float((__float_as_uint(acc[i][j][r]) & 0xFFFFF000u) | lidx);
            float o1 = s1[i][r];
            s2[i][r] = __builtin_amdgcn_fmed3f(o1, s2[i][r], key);
            s1[i][r] = fminf(o1, key);
          }
        }
    }
  }
#undef STAGE4

  // merge: dump per-lane top-2 to LDS [128 rows][32 keys] (stride 36), then
  // 128 row-threads keep top-4 via min/med3 chain and write packed keys.
  #pragma unroll
  for (int i = 0; i < 2; ++i)
    #pragma unroll
    for (int r = 0; r < 4; ++r) {
      int rib = wm * 32 + i * 16 + lg * 4 + r;
      int slot = t * 2;
      smem[rib * 36 + slot]     = s1[i][r];
      smem[rib * 36 + slot + 1] = s2[i][r];
    }
  __syncthreads();
  if (tid < 128) {
    float qd0 = INFINITY, qd1 = INFINITY, qd2 = INFINITY, qd3 = INFINITY;
    #pragma unroll
    for (int s = 0; s < 32; ++s) {
      float k = smem[tid * 36 + s];
      float o1 = qd0, o2 = qd1, o3 = qd2;
      qd0 = fminf(o1, k);
      qd1 = __builtin_amdgcn_fmed3f(o1, o2, k);
      qd2 = __builtin_amdgcn_fmed3f(o2, o3, k);
      qd3 = __builtin_amdgcn_fmed3f(o3, qd3, k);
    }
    float4 o = {qd0, qd1, qd2, qd3};
    *reinterpret_cast<float4*>(&ckeys[(size_t)(rb * 128 + tid) * 40 + grp * 4]) = o;
  }
}

// ------- lane-parallel top-4 select + exact fp64 rescore + gather + loss -------
__global__ __launch_bounds__(256) void rescore(const float* __restrict__ embeds,
                                               const float* __restrict__ cb0,
                                               const float* __restrict__ cb1,
                                               const float* __restrict__ cb2,
                                               const float* __restrict__ ckeys,
                                               float* __restrict__ out,
                                               float* __restrict__ lossp) {
  const int wv = threadIdx.x >> 6, ln = threadIdx.x & 63;
  const int gid = blockIdx.x * 4 + wv;            // 0..49151
  const int layer = gid >> 14, row = gid & (NROWS - 1);
  const float* cb; int K, slot0, nslot;
  if (layer == 0)      { cb = cb0; K = 5832; slot0 = 0;  nslot = 32; }
  else if (layer == 1) { cb = cb1; K = 324;  slot0 = 32; nslot = 4; }
  else                 { cb = cb2; K = 18;   slot0 = 36; nslot = 4; }

  // lane ln owns key-slot ln (coalesced); packed-key float-min == lex (dist,lidx);
  // equal keys -> same lidx -> lowest lane = lowest group = smallest global idx.
  float key = INFINITY;
  int gbase = 0;
  if (ln < nslot) {
    key = ckeys[(size_t)row * 40 + slot0 + ln];
    gbase = (layer == 0) ? ((ln >> 2) * 768) : 0;
  }
  int gidx = gbase + (int)(__float_as_uint(key) & 0xFFFu);

  int c0, c1, c2, c3;
#define ROUND(CVAR) do {                                                      \
    float m = key;                                                            \
    _Pragma("unroll")                                                         \
    for (int s = 32; s > 0; s >>= 1) m = fminf(m, __shfl_xor(m, s));          \
    unsigned long long msk = __ballot(key == m);                              \
    int owner = (int)__ffsll((long long)msk) - 1;                             \
    CVAR = __shfl(gidx, owner);                                               \
    if (ln == owner) key = INFINITY;                                          \
  } while (0)
  ROUND(c0); ROUND(c1); ROUND(c2); ROUND(c3);
#undef ROUND

  // 4 cand-groups x 16 lanes; lane covers dims [li*16, li*16+16)
  const int cg = ln >> 4, li = ln & 15;
  int ki = (cg == 0) ? c0 : (cg == 1) ? c1 : (cg == 2) ? c2 : c3;
  bool valid = (ki >= 0) && (ki < K);
  int ks = valid ? ki : 0;

  float4 e4[4], w4[4];
  #pragma unroll
  for (int q = 0; q < 4; ++q) {
    e4[q] = *reinterpret_cast<const float4*>(embeds + (size_t)row * DDIM + li * 16 + q * 4);
    w4[q] = *reinterpret_cast<const float4*>(cb + (size_t)ks * DDIM + li * 16 + q * 4);
  }
  double d = 0.0;
  #pragma unroll
  for (int q = 0; q < 4; ++q) {
    double x0 = (double)e4[q].x - (double)w4[q].x;
    double x1 = (double)e4[q].y - (double)w4[q].y;
    double x2 = (double)e4[q].z - (double)w4[q].z;
    double x3 = (double)e4[q].w - (double)w4[q].w;
    d += x0 * x0 + x1 * x1 + x2 * x2 + x3 * x3;
  }
  if (!valid) d = (double)INFINITY;
  #pragma unroll
  for (int m = 1; m < 16; m <<= 1) d += __shfl_xor(d, m);   // sum within cand-group

  double bd = d; int bk = valid ? ki : 0x7fffffff; int bcg = cg;
  #pragma unroll
  for (int m = 16; m < 64; m <<= 1) {                       // argmin across groups
    double od = __shfl_xor(bd, m);
    int ok  = __shfl_xor(bk, m);
    int ocg = __shfl_xor(bcg, m);
    bool better = (od < bd) || (od == bd && ok < bk);
    bd = better ? od : bd; bk = better ? ok : bk; bcg = better ? ocg : bcg;
  }
  if (bcg == cg) {                                          // winning group's 16 lanes write
    #pragma unroll
    for (int q = 0; q < 4; ++q)
      *reinterpret_cast<float4*>(out + (size_t)gid * DDIM + li * 16 + q * 4) = w4[q];
  }
  __shared__ float red[4];
  if (ln == 0) red[wv] = (float)bd;
  __syncthreads();
  if (threadIdx.x == 0) lossp[blockIdx.x] = red[0] + red[1] + red[2] + red[3];
}

__global__ __launch_bounds__(256) void loss_reduce(const float* __restrict__ lossp,
                                                   float* __restrict__ outloss) {
  __shared__ float red[256];
  const int tid = threadIdx.x;
  float s = 0.f;
  for (int i = tid; i < 12288; i += 256) s += lossp[i];
  red[tid] = s;
  __syncthreads();
  for (int st = 128; st > 0; st >>= 1) {
    if (tid < st) red[tid] += red[tid + st];
    __syncthreads();
  }
  if (tid == 0) outloss[0] = red[0] * (1.25f / ((float)NROWS * (float)DDIM));
}

extern "C" void kernel_launch(void* const* d_in, const int* in_sizes, int n_in,
                              void* d_out, int out_size, void* d_ws, size_t ws_size,
                              hipStream_t stream) {
  const float* embeds = (const float*)d_in[0];
  const float* cb0    = (const float*)d_in[1];
  const float* cb1    = (const float*)d_in[2];
  const float* cb2    = (const float*)d_in[3];
  float* out  = (float*)d_out;
  float* loss = out + (size_t)3 * NROWS * DDIM;

  char* ws = (char*)d_ws;
  unsigned short* Ehi  = (unsigned short*)(ws);               //  8,388,608 B
  unsigned short* W0   = (unsigned short*)(ws + 8388608);     //  3,145,728 B
  unsigned short* W12  = (unsigned short*)(ws + 11534336);    //    262,144 B
  float*          wsq0 = (float*)(ws + 11796480);             //     24,576 B
  float*          wsq12= (float*)(ws + 11821056);             //      2,048 B
  float*          ckeys= (float*)(ws + 11823104);             //  2,621,440 B
  float*          lp   = (float*)(ws + 14444544);             //     49,152 B

  (void)in_sizes; (void)n_in; (void)out_size; (void)ws_size;

  prep_all<<<3712, 256, 0, stream>>>(embeds, cb0, cb1, cb2, Ehi, W0, W12, wsq0, wsq12);
  gemm_scan<<<dim3(128, 10), 256, 0, stream>>>(Ehi, W0, W12, wsq0, wsq12, ckeys);
  rescore<<<12288, 256, 0, stream>>>(embeds, cb0, cb1, cb2, ckeys, out, lp);
  loss_reduce<<<1, 256, 0, stream>>>(lp, loss);
}

// Round 11
// 119.686 us; speedup vs baseline: 1.1763x; 1.1763x over previous
//
#include <hip/hip_runtime.h>
#include <math.h>

#define NROWS 16384
#define DDIM  256

typedef __attribute__((ext_vector_type(8))) short bf16x8;
typedef __attribute__((ext_vector_type(4))) float f32x4;
typedef __attribute__((ext_vector_type(4))) unsigned short us4;

__device__ __forceinline__ unsigned short bf16_rne(float f) {
  unsigned x = __float_as_uint(f);
  unsigned r = x + 0x7fffu + ((x >> 16) & 1u);
  return (unsigned short)(r >> 16);
}

typedef __attribute__((address_space(3))) unsigned int lds_uint;
typedef __attribute__((address_space(1))) const unsigned int glb_uint;
__device__ __forceinline__ void gload16(const void* g, void* l) {
  __builtin_amdgcn_global_load_lds((glb_uint*)g, (lds_uint*)l, 16, 0, 0);
}

// ------------- fused prep: embeds->bf16 hi  AND  padded -2W + ||w||^2 -------------
__global__ __launch_bounds__(256) void prep_all(const float* __restrict__ e,
                                                const float* __restrict__ cb0,
                                                const float* __restrict__ cb1,
                                                const float* __restrict__ cb2,
                                                unsigned short* __restrict__ ehi,
                                                unsigned short* __restrict__ W0,
                                                unsigned short* __restrict__ W12,
                                                float* __restrict__ wsq0,
                                                float* __restrict__ wsq12) {
  if (blockIdx.x < 2048) {
    int gid = blockIdx.x * 256 + threadIdx.x;
    const float4* p = reinterpret_cast<const float4*>(e) + (size_t)gid * 2;
    float4 a = p[0], b = p[1];
    float f[8] = {a.x, a.y, a.z, a.w, b.x, b.y, b.z, b.w};
    unsigned short hi[8];
    #pragma unroll
    for (int i = 0; i < 8; ++i) hi[i] = bf16_rne(f[i]);
    us4 h0 = {hi[0], hi[1], hi[2], hi[3]}, h1 = {hi[4], hi[5], hi[6], hi[7]};
    *reinterpret_cast<us4*>(&ehi[(size_t)gid * 8]) = h0;
    *reinterpret_cast<us4*>(&ehi[(size_t)gid * 8 + 4]) = h1;
    return;
  }
  int wv = threadIdx.x >> 6, ln = threadIdx.x & 63;
  int p = (blockIdx.x - 2048) * 4 + wv;          // 0..6655
  const float* src = nullptr; int local = 0;
  unsigned short* dst; float* wdst; int dcol;
  if (p < 6144) {
    dst = W0; wdst = wsq0; dcol = p;
    if (p < 5832) { src = cb0; local = p; }
  } else {
    int q = p - 6144;                            // 0..511
    dst = W12; wdst = wsq12; dcol = q;
    if (q < 324) { src = cb1; local = q; }
    else if (q >= 384 && q < 402) { src = cb2; local = q - 384; }
  }
  float4 f = make_float4(0.f, 0.f, 0.f, 0.f);
  if (src) f = *reinterpret_cast<const float4*>(src + (size_t)local * DDIM + ln * 4);
  // store -2w: MFMA then accumulates -2*e.w onto the ||w||^2 seed directly
  us4 h = {bf16_rne(-2.0f * f.x), bf16_rne(-2.0f * f.y),
           bf16_rne(-2.0f * f.z), bf16_rne(-2.0f * f.w)};
  *reinterpret_cast<us4*>(&dst[(size_t)dcol * DDIM + ln * 4]) = h;
  float s = f.x * f.x + f.y * f.y + f.z * f.z + f.w * f.w;
  #pragma unroll
  for (int m = 32; m > 0; m >>= 1) s += __shfl_xor(s, m);
  if (ln == 0) wdst[dcol] = src ? s : 1e38f;
}

// ------------- MFMA GEMM + in-lane packed-key top-2 scan (r9-exact) -------------
// grid (128 rowblocks, 10 colgroups); 256 thr = 4 m-waves; wave = 32 rows x
// 64 cols; A full-K in VGPRs; B in 2x16KB LDS buffers: stage 4 / consume 4
// BK=32 chunks (32 MFMA) per barrier; acc seeded with ||w||^2.
// NOTE: (256,3) is load-bearing — (256,4) caps VGPR at 128 and spills (r8, r10).
__global__ __launch_bounds__(256, 3) void gemm_scan(
    const unsigned short* __restrict__ Ehi,
    const unsigned short* __restrict__ W0,
    const unsigned short* __restrict__ W12,
    const float* __restrict__ wsq0,
    const float* __restrict__ wsq12,
    float* __restrict__ ckeys) {
  __shared__ float smem[8192];                   // 32 KB: 2x16KB ring; merge unions
  unsigned short* Bs = reinterpret_cast<unsigned short*>(smem);

  const int tid = threadIdx.x;
  const int wm = tid >> 6, ln = tid & 63;
  const int t = ln & 15, lg = ln >> 4;
  const int rb = blockIdx.x, grp = blockIdx.y;

  const unsigned short* Wb; const float* wsqb; int nnt;
  if (grp < 8)       { Wb = W0 + (size_t)grp * 768 * 256; wsqb = wsq0 + grp * 768; nnt = 12; }
  else if (grp == 8) { Wb = W12;             wsqb = wsq12;       nnt = 6; }
  else               { Wb = W12 + 384 * 256; wsqb = wsq12 + 384; nnt = 1; }

  // A fragments: rows rb*128 + wm*32 + i*16 + t, k = ks*32 + lg*8 (full K in VGPRs)
  bf16x8 af[2][8];
  {
    const unsigned short* abase = Ehi + (size_t)(rb * 128 + wm * 32 + t) * 256 + lg * 8;
    #pragma unroll
    for (int i = 0; i < 2; ++i)
      #pragma unroll
      for (int ks = 0; ks < 8; ++ks)
        af[i][ks] = *reinterpret_cast<const bf16x8*>(abase + i * 16 * 256 + ks * 32);
  }

  // staging source (both-sides chunk swizzle; LDS dest stays linear)
  const int scol = tid >> 2;
  const int scs  = ((tid & 3) ^ ((scol >> 1) & 3)) * 8;

#define STAGE4(buf, cc0) do {                                                  \
    _Pragma("unroll")                                                          \
    for (int c = 0; c < 4; ++c) {                                              \
      const int cc = (cc0) + c;                                                \
      const unsigned short* wsrc = Wb + (cc >> 3) * (64 * 256) + (cc & 7) * 32;\
      gload16(wsrc + (size_t)scol * 256 + scs,                                 \
              Bs + ((buf) * 4 + c) * 2048 + tid * 8);                          \
    } } while (0)

  f32x4 acc[2][4];
  float s1[2][4], s2[2][4];
  #pragma unroll
  for (int i = 0; i < 2; ++i)
    #pragma unroll
    for (int r = 0; r < 4; ++r) { s1[i][r] = INFINITY; s2[i][r] = INFINITY; }

  const int nper = nnt * 2;                      // 4-chunk periods
  STAGE4(0, 0);
  __syncthreads();
  for (int ntl = 0; ntl < nnt; ++ntl) {
    float wq[4];
    #pragma unroll
    for (int j = 0; j < 4; ++j) wq[j] = wsqb[ntl * 64 + j * 16 + t];
    #pragma unroll
    for (int i = 0; i < 2; ++i)
      #pragma unroll
      for (int j = 0; j < 4; ++j)
        acc[i][j] = (f32x4){wq[j], wq[j], wq[j], wq[j]};   // seed with ||w||^2

    #pragma unroll
    for (int dd = 0; dd < 2; ++dd) {
      const int period = ntl * 2 + dd;
      if (period + 1 < nper) STAGE4((period + 1) & 1, (period + 1) * 4);
      const int bb = period & 1;
      #pragma unroll
      for (int c = 0; c < 4; ++c) {
        const int ks = dd * 4 + c;
        bf16x8 bfr[4];
        #pragma unroll
        for (int j = 0; j < 4; ++j) {
          int col = j * 16 + t;
          bfr[j] = *reinterpret_cast<const bf16x8*>(
              Bs + (bb * 4 + c) * 2048 + col * 32 + ((lg ^ ((col >> 1) & 3)) << 3));
        }
        #pragma unroll
        for (int i = 0; i < 2; ++i)
          #pragma unroll
          for (int j = 0; j < 4; ++j)
            acc[i][j] = __builtin_amdgcn_mfma_f32_16x16x32_bf16(af[i][ks], bfr[j], acc[i][j], 0, 0, 0);
      }
      __syncthreads();                           // staged quad landed; readers done
    }
    // scan: acc IS the distance; key = (acc & ~0xFFF) | local_col_idx
    {
      const unsigned lbase = (unsigned)(ntl * 64 + t);
      #pragma unroll
      for (int i = 0; i < 2; ++i)
        #pragma unroll
        for (int j = 0; j < 4; ++j) {
          const unsigned lidx = lbase + j * 16;
          #pragma unroll
          for (int r = 0; r < 4; ++r) {
            float key = __uint_as_float((__float_as_uint(acc[i][j][r]) & 0xFFFFF000u) | lidx);
            float o1 = s1[i][r];
            s2[i][r] = __builtin_amdgcn_fmed3f(o1, s2[i][r], key);
            s1[i][r] = fminf(o1, key);
          }
        }
    }
  }
#undef STAGE4

  // merge: dump per-lane top-2 to LDS [128 rows][32 keys] (stride 36), then
  // 128 row-threads keep top-4 via min/med3 chain and write packed keys.
  #pragma unroll
  for (int i = 0; i < 2; ++i)
    #pragma unroll
    for (int r = 0; r < 4; ++r) {
      int rib = wm * 32 + i * 16 + lg * 4 + r;
      int slot = t * 2;
      smem[rib * 36 + slot]     = s1[i][r];
      smem[rib * 36 + slot + 1] = s2[i][r];
    }
  __syncthreads();
  if (tid < 128) {
    float qd0 = INFINITY, qd1 = INFINITY, qd2 = INFINITY, qd3 = INFINITY;
    #pragma unroll
    for (int s = 0; s < 32; ++s) {
      float k = smem[tid * 36 + s];
      float o1 = qd0, o2 = qd1, o3 = qd2;
      qd0 = fminf(o1, k);
      qd1 = __builtin_amdgcn_fmed3f(o1, o2, k);
      qd2 = __builtin_amdgcn_fmed3f(o2, o3, k);
      qd3 = __builtin_amdgcn_fmed3f(o3, qd3, k);
    }
    float4 o = {qd0, qd1, qd2, qd3};
    *reinterpret_cast<float4*>(&ckeys[(size_t)(rb * 128 + tid) * 40 + grp * 4]) = o;
  }
}

// ------- lane-parallel top-4 select + fp32 direct-diff rescore + gather + loss -------
__global__ __launch_bounds__(256) void rescore(const float* __restrict__ embeds,
                                               const float* __restrict__ cb0,
                                               const float* __restrict__ cb1,
                                               const float* __restrict__ cb2,
                                               const float* __restrict__ ckeys,
                                               float* __restrict__ out,
                                               float* __restrict__ lossp) {
  const int wv = threadIdx.x >> 6, ln = threadIdx.x & 63;
  const int gid = blockIdx.x * 4 + wv;            // 0..49151
  const int layer = gid >> 14, row = gid & (NROWS - 1);
  const float* cb; int K, slot0, nslot;
  if (layer == 0)      { cb = cb0; K = 5832; slot0 = 0;  nslot = 32; }
  else if (layer == 1) { cb = cb1; K = 324;  slot0 = 32; nslot = 4; }
  else                 { cb = cb2; K = 18;   slot0 = 36; nslot = 4; }

  // lane ln owns key-slot ln (coalesced); packed-key float-min == lex (dist,lidx);
  // equal keys -> same lidx -> lowest lane = lowest group = smallest global idx.
  float key = INFINITY;
  int gbase = 0;
  if (ln < nslot) {
    key = ckeys[(size_t)row * 40 + slot0 + ln];
    gbase = (layer == 0) ? ((ln >> 2) * 768) : 0;
  }
  int gidx = gbase + (int)(__float_as_uint(key) & 0xFFFu);

  int c0, c1, c2, c3;
#define ROUND(CVAR) do {                                                      \
    float m = key;                                                            \
    _Pragma("unroll")                                                         \
    for (int s = 32; s > 0; s >>= 1) m = fminf(m, __shfl_xor(m, s));          \
    unsigned long long msk = __ballot(key == m);                              \
    int owner = (int)__ffsll((long long)msk) - 1;                             \
    CVAR = __shfl(gidx, owner);                                               \
    if (ln == owner) key = INFINITY;                                          \
  } while (0)
  ROUND(c0); ROUND(c1); ROUND(c2); ROUND(c3);
#undef ROUND

  // 4 cand-groups x 16 lanes; lane covers dims [li*16, li*16+16)
  const int cg = ln >> 4, li = ln & 15;
  int ki = (cg == 0) ? c0 : (cg == 1) ? c1 : (cg == 2) ? c2 : c3;
  bool valid = (ki >= 0) && (ki < K);
  int ks = valid ? ki : 0;

  float4 e4[4], w4[4];
  #pragma unroll
  for (int q = 0; q < 4; ++q) {
    e4[q] = *reinterpret_cast<const float4*>(embeds + (size_t)row * DDIM + li * 16 + q * 4);
    w4[q] = *reinterpret_cast<const float4*>(cb + (size_t)ks * DDIM + li * 16 + q * 4);
  }
  // fp32 direct-diff distance: error ~1e-3 << candidate gaps (O(10)); exact
  // formula class, deterministic lex tie-break below.
  float d = 0.0f;
  #pragma unroll
  for (int q = 0; q < 4; ++q) {
    float x0 = e4[q].x - w4[q].x, x1 = e4[q].y - w4[q].y;
    float x2 = e4[q].z - w4[q].z, x3 = e4[q].w - w4[q].w;
    d = fmaf(x0, x0, d); d = fmaf(x1, x1, d);
    d = fmaf(x2, x2, d); d = fmaf(x3, x3, d);
  }
  if (!valid) d = INFINITY;
  #pragma unroll
  for (int m = 1; m < 16; m <<= 1) d += __shfl_xor(d, m);   // sum within cand-group

  float bd = d; int bk = valid ? ki : 0x7fffffff; int bcg = cg;
  #pragma unroll
  for (int m = 16; m < 64; m <<= 1) {                       // argmin across groups
    float od = __shfl_xor(bd, m);
    int ok  = __shfl_xor(bk, m);
    int ocg = __shfl_xor(bcg, m);
    bool better = (od < bd) || (od == bd && ok < bk);
    bd = better ? od : bd; bk = better ? ok : bk; bcg = better ? ocg : bcg;
  }
  if (bcg == cg) {                                          // winning group's 16 lanes write
    #pragma unroll
    for (int q = 0; q < 4; ++q)
      *reinterpret_cast<float4*>(out + (size_t)gid * DDIM + li * 16 + q * 4) = w4[q];
  }
  __shared__ float red[4];
  if (ln == 0) red[wv] = bd;
  __syncthreads();
  if (threadIdx.x == 0) lossp[blockIdx.x] = red[0] + red[1] + red[2] + red[3];
}

__global__ __launch_bounds__(256) void loss_reduce(const float* __restrict__ lossp,
                                                   float* __restrict__ outloss) {
  __shared__ float red[256];
  const int tid = threadIdx.x;
  float s = 0.f;
  for (int i = tid; i < 12288; i += 256) s += lossp[i];
  red[tid] = s;
  __syncthreads();
  for (int st = 128; st > 0; st >>= 1) {
    if (tid < st) red[tid] += red[tid + st];
    __syncthreads();
  }
  if (tid == 0) outloss[0] = red[0] * (1.25f / ((float)NROWS * (float)DDIM));
}

extern "C" void kernel_launch(void* const* d_in, const int* in_sizes, int n_in,
                              void* d_out, int out_size, void* d_ws, size_t ws_size,
                              hipStream_t stream) {
  const float* embeds = (const float*)d_in[0];
  const float* cb0    = (const float*)d_in[1];
  const float* cb1    = (const float*)d_in[2];
  const float* cb2    = (const float*)d_in[3];
  float* out  = (float*)d_out;
  float* loss = out + (size_t)3 * NROWS * DDIM;

  char* ws = (char*)d_ws;
  unsigned short* Ehi  = (unsigned short*)(ws);               //  8,388,608 B
  unsigned short* W0   = (unsigned short*)(ws + 8388608);     //  3,145,728 B
  unsigned short* W12  = (unsigned short*)(ws + 11534336);    //    262,144 B
  float*          wsq0 = (float*)(ws + 11796480);             //     24,576 B
  float*          wsq12= (float*)(ws + 11821056);             //      2,048 B
  float*          ckeys= (float*)(ws + 11823104);             //  2,621,440 B
  float*          lp   = (float*)(ws + 14444544);             //     49,152 B

  (void)in_sizes; (void)n_in; (void)out_size; (void)ws_size;

  prep_all<<<3712, 256, 0, stream>>>(embeds, cb0, cb1, cb2, Ehi, W0, W12, wsq0, wsq12);
  gemm_scan<<<dim3(128, 10), 256, 0, stream>>>(Ehi, W0, W12, wsq0, wsq12, ckeys);
  rescore<<<12288, 256, 0, stream>>>(embeds, cb0, cb1, cb2, ckeys, out, lp);
  loss_reduce<<<1, 256, 0, stream>>>(lp, loss);
}

// Round 12
// 101.572 us; speedup vs baseline: 1.3860x; 1.1783x over previous
//
#include <hip/hip_runtime.h>
#include <math.h>

#define NROWS 16384
#define DDIM  256

typedef __attribute__((ext_vector_type(8))) short bf16x8;
typedef __attribute__((ext_vector_type(4))) float f32x4;
typedef __attribute__((ext_vector_type(4))) unsigned short us4;

__device__ __forceinline__ unsigned short bf16_rne(float f) {
  unsigned x = __float_as_uint(f);
  unsigned r = x + 0x7fffu + ((x >> 16) & 1u);
  return (unsigned short)(r >> 16);
}

typedef __attribute__((address_space(3))) unsigned int lds_uint;
typedef __attribute__((address_space(1))) const unsigned int glb_uint;
__device__ __forceinline__ void gload16(const void* g, void* l) {
  __builtin_amdgcn_global_load_lds((glb_uint*)g, (lds_uint*)l, 16, 0, 0);
}

// ------------- fused prep: embeds->bf16 hi  AND  padded -2W + ||w||^2 -------------
__global__ __launch_bounds__(256) void prep_all(const float* __restrict__ e,
                                                const float* __restrict__ cb0,
                                                const float* __restrict__ cb1,
                                                const float* __restrict__ cb2,
                                                unsigned short* __restrict__ ehi,
                                                unsigned short* __restrict__ W0,
                                                unsigned short* __restrict__ W12,
                                                float* __restrict__ wsq0,
                                                float* __restrict__ wsq12) {
  if (blockIdx.x < 2048) {
    int gid = blockIdx.x * 256 + threadIdx.x;
    const float4* p = reinterpret_cast<const float4*>(e) + (size_t)gid * 2;
    float4 a = p[0], b = p[1];
    float f[8] = {a.x, a.y, a.z, a.w, b.x, b.y, b.z, b.w};
    unsigned short hi[8];
    #pragma unroll
    for (int i = 0; i < 8; ++i) hi[i] = bf16_rne(f[i]);
    us4 h0 = {hi[0], hi[1], hi[2], hi[3]}, h1 = {hi[4], hi[5], hi[6], hi[7]};
    *reinterpret_cast<us4*>(&ehi[(size_t)gid * 8]) = h0;
    *reinterpret_cast<us4*>(&ehi[(size_t)gid * 8 + 4]) = h1;
    return;
  }
  int wv = threadIdx.x >> 6, ln = threadIdx.x & 63;
  int p = (blockIdx.x - 2048) * 4 + wv;          // 0..6655
  const float* src = nullptr; int local = 0;
  unsigned short* dst; float* wdst; int dcol;
  if (p < 6144) {
    dst = W0; wdst = wsq0; dcol = p;
    if (p < 5832) { src = cb0; local = p; }
  } else {
    int q = p - 6144;                            // 0..511
    dst = W12; wdst = wsq12; dcol = q;
    if (q < 324) { src = cb1; local = q; }
    else if (q >= 384 && q < 402) { src = cb2; local = q - 384; }
  }
  float4 f = make_float4(0.f, 0.f, 0.f, 0.f);
  if (src) f = *reinterpret_cast<const float4*>(src + (size_t)local * DDIM + ln * 4);
  // store -2w: MFMA then accumulates -2*e.w onto the ||w||^2 seed directly
  us4 h = {bf16_rne(-2.0f * f.x), bf16_rne(-2.0f * f.y),
           bf16_rne(-2.0f * f.z), bf16_rne(-2.0f * f.w)};
  *reinterpret_cast<us4*>(&dst[(size_t)dcol * DDIM + ln * 4]) = h;
  float s = f.x * f.x + f.y * f.y + f.z * f.z + f.w * f.w;
  #pragma unroll
  for (int m = 32; m > 0; m >>= 1) s += __shfl_xor(s, m);
  if (ln == 0) wdst[dcol] = src ? s : 1e38f;
}

// ------------- MFMA GEMM + in-lane packed-key top-2 scan (r9-exact) -------------
// grid (128 rowblocks, 10 colgroups); 256 thr = 4 m-waves; wave = 32 rows x
// 64 cols; A full-K in VGPRs; B in 2x16KB LDS buffers: stage 4 / consume 4
// BK=32 chunks (32 MFMA) per barrier; acc seeded with ||w||^2.
// NOTE: (256,3) is load-bearing — (256,4) caps VGPR at 128 and spills (r8, r10).
__global__ __launch_bounds__(256, 3) void gemm_scan(
    const unsigned short* __restrict__ Ehi,
    const unsigned short* __restrict__ W0,
    const unsigned short* __restrict__ W12,
    const float* __restrict__ wsq0,
    const float* __restrict__ wsq12,
    float* __restrict__ ckeys) {
  __shared__ float smem[8192];                   // 32 KB: 2x16KB ring; merge unions
  unsigned short* Bs = reinterpret_cast<unsigned short*>(smem);

  const int tid = threadIdx.x;
  const int wm = tid >> 6, ln = tid & 63;
  const int t = ln & 15, lg = ln >> 4;
  const int rb = blockIdx.x, grp = blockIdx.y;

  const unsigned short* Wb; const float* wsqb; int nnt;
  if (grp < 8)       { Wb = W0 + (size_t)grp * 768 * 256; wsqb = wsq0 + grp * 768; nnt = 12; }
  else if (grp == 8) { Wb = W12;             wsqb = wsq12;       nnt = 6; }
  else               { Wb = W12 + 384 * 256; wsqb = wsq12 + 384; nnt = 1; }

  // A fragments: rows rb*128 + wm*32 + i*16 + t, k = ks*32 + lg*8 (full K in VGPRs)
  bf16x8 af[2][8];
  {
    const unsigned short* abase = Ehi + (size_t)(rb * 128 + wm * 32 + t) * 256 + lg * 8;
    #pragma unroll
    for (int i = 0; i < 2; ++i)
      #pragma unroll
      for (int ks = 0; ks < 8; ++ks)
        af[i][ks] = *reinterpret_cast<const bf16x8*>(abase + i * 16 * 256 + ks * 32);
  }

  // staging source (both-sides chunk swizzle; LDS dest stays linear)
  const int scol = tid >> 2;
  const int scs  = ((tid & 3) ^ ((scol >> 1) & 3)) * 8;

#define STAGE4(buf, cc0) do {                                                  \
    _Pragma("unroll")                                                          \
    for (int c = 0; c < 4; ++c) {                                              \
      const int cc = (cc0) + c;                                                \
      const unsigned short* wsrc = Wb + (cc >> 3) * (64 * 256) + (cc & 7) * 32;\
      gload16(wsrc + (size_t)scol * 256 + scs,                                 \
              Bs + ((buf) * 4 + c) * 2048 + tid * 8);                          \
    } } while (0)

  f32x4 acc[2][4];
  float s1[2][4], s2[2][4];
  #pragma unroll
  for (int i = 0; i < 2; ++i)
    #pragma unroll
    for (int r = 0; r < 4; ++r) { s1[i][r] = INFINITY; s2[i][r] = INFINITY; }

  const int nper = nnt * 2;                      // 4-chunk periods
  STAGE4(0, 0);
  __syncthreads();
  for (int ntl = 0; ntl < nnt; ++ntl) {
    float wq[4];
    #pragma unroll
    for (int j = 0; j < 4; ++j) wq[j] = wsqb[ntl * 64 + j * 16 + t];
    #pragma unroll
    for (int i = 0; i < 2; ++i)
      #pragma unroll
      for (int j = 0; j < 4; ++j)
        acc[i][j] = (f32x4){wq[j], wq[j], wq[j], wq[j]};   // seed with ||w||^2

    #pragma unroll
    for (int dd = 0; dd < 2; ++dd) {
      const int period = ntl * 2 + dd;
      if (period + 1 < nper) STAGE4((period + 1) & 1, (period + 1) * 4);
      const int bb = period & 1;
      #pragma unroll
      for (int c = 0; c < 4; ++c) {
        const int ks = dd * 4 + c;
        bf16x8 bfr[4];
        #pragma unroll
        for (int j = 0; j < 4; ++j) {
          int col = j * 16 + t;
          bfr[j] = *reinterpret_cast<const bf16x8*>(
              Bs + (bb * 4 + c) * 2048 + col * 32 + ((lg ^ ((col >> 1) & 3)) << 3));
        }
        #pragma unroll
        for (int i = 0; i < 2; ++i)
          #pragma unroll
          for (int j = 0; j < 4; ++j)
            acc[i][j] = __builtin_amdgcn_mfma_f32_16x16x32_bf16(af[i][ks], bfr[j], acc[i][j], 0, 0, 0);
      }
      __syncthreads();                           // staged quad landed; readers done
    }
    // scan: acc IS the distance; key = (acc & ~0xFFF) | local_col_idx
    {
      const unsigned lbase = (unsigned)(ntl * 64 + t);
      #pragma unroll
      for (int i = 0; i < 2; ++i)
        #pragma unroll
        for (int j = 0; j < 4; ++j) {
          const unsigned lidx = lbase + j * 16;
          #pragma unroll
          for (int r = 0; r < 4; ++r) {
            float key = __uint_as_float((__float_as_uint(acc[i][j][r]) & 0xFFFFF000u) | lidx);
            float o1 = s1[i][r];
            s2[i][r] = __builtin_amdgcn_fmed3f(o1, s2[i][r], key);
            s1[i][r] = fminf(o1, key);
          }
        }
    }
  }
#undef STAGE4

  // merge: dump per-lane top-2 to LDS [128 rows][32 keys] (stride 36), then
  // 128 row-threads keep top-4 via min/med3 chain and write packed keys.
  #pragma unroll
  for (int i = 0; i < 2; ++i)
    #pragma unroll
    for (int r = 0; r < 4; ++r) {
      int rib = wm * 32 + i * 16 + lg * 4 + r;
      int slot = t * 2;
      smem[rib * 36 + slot]     = s1[i][r];
      smem[rib * 36 + slot + 1] = s2[i][r];
    }
  __syncthreads();
  if (tid < 128) {
    float qd0 = INFINITY, qd1 = INFINITY, qd2 = INFINITY, qd3 = INFINITY;
    #pragma unroll
    for (int s = 0; s < 32; ++s) {
      float k = smem[tid * 36 + s];
      float o1 = qd0, o2 = qd1, o3 = qd2;
      qd0 = fminf(o1, k);
      qd1 = __builtin_amdgcn_fmed3f(o1, o2, k);
      qd2 = __builtin_amdgcn_fmed3f(o2, o3, k);
      qd3 = __builtin_amdgcn_fmed3f(o3, qd3, k);
    }
    float4 o = {qd0, qd1, qd2, qd3};
    *reinterpret_cast<float4*>(&ckeys[(size_t)(rb * 128 + tid) * 40 + grp * 4]) = o;
  }
}

// --- one wave per ROW, all 3 layers: top-4 select + fp32 rescore + gather + loss ---
__global__ __launch_bounds__(256) void rescore(const float* __restrict__ embeds,
                                               const float* __restrict__ cb0,
                                               const float* __restrict__ cb1,
                                               const float* __restrict__ cb2,
                                               const float* __restrict__ ckeys,
                                               float* __restrict__ out,
                                               float* __restrict__ lossp) {
  const int wv = threadIdx.x >> 6, ln = threadIdx.x & 63;
  const int row = blockIdx.x * 4 + wv;            // 0..16383
  const int cg = ln >> 4, li = ln & 15;           // 4 cand-groups x 16 lanes

  // one coalesced read of this row's 40 packed keys (lane ln owns slot ln)
  float keyrow = (ln < 40) ? ckeys[(size_t)row * 40 + ln] : INFINITY;

  // e fragments once, held across all 3 layers
  float4 e4[4];
  #pragma unroll
  for (int q = 0; q < 4; ++q)
    e4[q] = *reinterpret_cast<const float4*>(embeds + (size_t)row * DDIM + li * 16 + q * 4);

  float loss_sum = 0.0f;

  #pragma unroll
  for (int l = 0; l < 3; ++l) {
    const float* cb; int K;
    float key; int gbase;
    if (l == 0)      { cb = cb0; K = 5832; key = (ln < 32) ? keyrow : INFINITY; gbase = (ln >> 2) * 768; }
    else if (l == 1) { cb = cb1; K = 324;  key = (ln >= 32 && ln < 36) ? keyrow : INFINITY; gbase = 0; }
    else             { cb = cb2; K = 18;   key = (ln >= 36) ? keyrow : INFINITY; gbase = 0; }
    int gidx = gbase + (int)(__float_as_uint(key) & 0xFFFu);

    int c0, c1, c2, c3;
#define ROUND(CVAR) do {                                                      \
    float m = key;                                                            \
    _Pragma("unroll")                                                         \
    for (int s = 32; s > 0; s >>= 1) m = fminf(m, __shfl_xor(m, s));          \
    unsigned long long msk = __ballot(key == m);                              \
    int owner = (int)__ffsll((long long)msk) - 1;                             \
    CVAR = __shfl(gidx, owner);                                               \
    if (ln == owner) key = INFINITY;                                          \
  } while (0)
    ROUND(c0); ROUND(c1); ROUND(c2); ROUND(c3);
#undef ROUND

    int ki = (cg == 0) ? c0 : (cg == 1) ? c1 : (cg == 2) ? c2 : c3;
    bool valid = (ki >= 0) && (ki < K);
    int ks = valid ? ki : 0;

    float4 w4[4];
    #pragma unroll
    for (int q = 0; q < 4; ++q)
      w4[q] = *reinterpret_cast<const float4*>(cb + (size_t)ks * DDIM + li * 16 + q * 4);

    // fp32 direct-diff distance: error ~1e-3 << candidate gaps (O(10))
    float d = 0.0f;
    #pragma unroll
    for (int q = 0; q < 4; ++q) {
      float x0 = e4[q].x - w4[q].x, x1 = e4[q].y - w4[q].y;
      float x2 = e4[q].z - w4[q].z, x3 = e4[q].w - w4[q].w;
      d = fmaf(x0, x0, d); d = fmaf(x1, x1, d);
      d = fmaf(x2, x2, d); d = fmaf(x3, x3, d);
    }
    if (!valid) d = INFINITY;
    #pragma unroll
    for (int m = 1; m < 16; m <<= 1) d += __shfl_xor(d, m);  // sum within cand-group

    float bd = d; int bk = valid ? ki : 0x7fffffff; int bcg = cg;
    #pragma unroll
    for (int m = 16; m < 64; m <<= 1) {                      // argmin across groups
      float od = __shfl_xor(bd, m);
      int ok  = __shfl_xor(bk, m);
      int ocg = __shfl_xor(bcg, m);
      bool better = (od < bd) || (od == bd && ok < bk);
      bd = better ? od : bd; bk = better ? ok : bk; bcg = better ? ocg : bcg;
    }
    if (bcg == cg) {                                         // winning group writes row
      #pragma unroll
      for (int q = 0; q < 4; ++q)
        *reinterpret_cast<float4*>(out + ((size_t)l * NROWS + row) * DDIM + li * 16 + q * 4) = w4[q];
    }
    loss_sum += bd;
  }

  __shared__ float red[4];
  if (ln == 0) red[wv] = loss_sum;
  __syncthreads();
  if (threadIdx.x == 0) lossp[blockIdx.x] = red[0] + red[1] + red[2] + red[3];
}

__global__ __launch_bounds__(256) void loss_reduce(const float* __restrict__ lossp,
                                                   float* __restrict__ outloss) {
  __shared__ float red[256];
  const int tid = threadIdx.x;
  float s = 0.f;
  for (int i = tid; i < 4096; i += 256) s += lossp[i];
  red[tid] = s;
  __syncthreads();
  for (int st = 128; st > 0; st >>= 1) {
    if (tid < st) red[tid] += red[tid + st];
    __syncthreads();
  }
  if (tid == 0) outloss[0] = red[0] * (1.25f / ((float)NROWS * (float)DDIM));
}

extern "C" void kernel_launch(void* const* d_in, const int* in_sizes, int n_in,
                              void* d_out, int out_size, void* d_ws, size_t ws_size,
                              hipStream_t stream) {
  const float* embeds = (const float*)d_in[0];
  const float* cb0    = (const float*)d_in[1];
  const float* cb1    = (const float*)d_in[2];
  const float* cb2    = (const float*)d_in[3];
  float* out  = (float*)d_out;
  float* loss = out + (size_t)3 * NROWS * DDIM;

  char* ws = (char*)d_ws;
  unsigned short* Ehi  = (unsigned short*)(ws);               //  8,388,608 B
  unsigned short* W0   = (unsigned short*)(ws + 8388608);     //  3,145,728 B
  unsigned short* W12  = (unsigned short*)(ws + 11534336);    //    262,144 B
  float*          wsq0 = (float*)(ws + 11796480);             //     24,576 B
  float*          wsq12= (float*)(ws + 11821056);             //      2,048 B
  float*          ckeys= (float*)(ws + 11823104);             //  2,621,440 B
  float*          lp   = (float*)(ws + 14444544);             //     16,384 B

  (void)in_sizes; (void)n_in; (void)out_size; (void)ws_size;

  prep_all<<<3712, 256, 0, stream>>>(embeds, cb0, cb1, cb2, Ehi, W0, W12, wsq0, wsq12);
  gemm_scan<<<dim3(128, 10), 256, 0, stream>>>(Ehi, W0, W12, wsq0, wsq12, ckeys);
  rescore<<<4096, 256, 0, stream>>>(embeds, cb0, cb1, cb2, ckeys, out, lp);
  loss_reduce<<<1, 256, 0, stream>>>(lp, loss);
}